// Round 5
// baseline (20.084 us; speedup 1.0000x reference)
//
#include <hip/hip_runtime.h>

// PrRoIPool forward. features [2,64,100,100] f32, rois [256,5], out [256,64,7,7].
//
// Separable analytic integral of bilinear interp over each bin; fixed windows
// (8 px in y, 10 px in x with even start so f16 row loads are 4B-aligned);
// out-of-support pixels get exactly-zero weights -> exact.
//
// Round-5: r1-r4 showed time is invariant to VMEM/VALU instruction count and
// L2 locality (~15 us). Remaining theories: L1 data-return bytes (205 MB @
// ~39 TB/s ~= 5.3 us term) vs fixed dispatch overhead. This round halves the
// byte term: pre-kernel converts features to f16 in d_ws (rel err 5e-4,
// output err ~2e-3 vs 5.06e-2 threshold), main kernel loads 20B f16 rows and
// reduces with v_dot2_f32_f16. Mapping + XCD swizzle identical to r4.

constexpr int OUT_H = 7, OUT_W = 7;
constexpr float SPATIAL_SCALE = 0.25f;
constexpr int CH = 64, FH = 100, FW = 100;
constexpr int SUP = 8;    // y window
constexpr int SUPX = 10;  // x window, even start -> 4B-aligned
constexpr int N_XCD = 8;

typedef _Float16 h8 __attribute__((ext_vector_type(8), aligned(4)));
typedef _Float16 h8a __attribute__((ext_vector_type(8), aligned(16)));
typedef _Float16 h2 __attribute__((ext_vector_type(2), aligned(4)));

__device__ __forceinline__ float dot2f(h2 a, h2 b, float c) {
#if defined(__has_builtin) && __has_builtin(__builtin_amdgcn_fdot2)
    return __builtin_amdgcn_fdot2(a, b, c, false);
#else
    return fmaf((float)a.x, (float)b.x, fmaf((float)a.y, (float)b.y, c));
#endif
}

__device__ __forceinline__ float hat_cdf_c(float t) {
    // cdf(t) - 0.5 (constant cancels in differences): s=clamp(t,-1,1),
    // s*(1-|s|/2).  min(max()) -> v_med3_f32; |s| is a free input modifier.
    float s = fminf(fmaxf(t, -1.0f), 1.0f);
    return s * fmaf(-0.5f, fabsf(s), 1.0f);
}

__global__ __launch_bounds__(256) void cvt_f32_f16_kernel(
    const float* __restrict__ in, _Float16* __restrict__ out, int n8) {
    int i = blockIdx.x * 256 + threadIdx.x;
    if (i >= n8) return;
    const float4* p = reinterpret_cast<const float4*>(in) + (size_t)i * 2;
    float4 a = p[0], b = p[1];
    h8a o = {(_Float16)a.x, (_Float16)a.y, (_Float16)a.z, (_Float16)a.w,
             (_Float16)b.x, (_Float16)b.y, (_Float16)b.z, (_Float16)b.w};
    reinterpret_cast<h8a*>(out)[i] = o;
}

__global__ __launch_bounds__(256) void prroi_pool_kernel(
    const _Float16* __restrict__ feat, const float* __restrict__ rois,
    float* __restrict__ out, int n_rois) {
    // Bijective XCD swizzle (nwg = 3136 = 8*392) + c-major decode: XCD k
    // touches only channels [8k, 8k+8) -> per-XCD working set L2-resident.
    int nwg = gridDim.x;
    int cpx = nwg / N_XCD;
    int chunk = (blockIdx.x % N_XCD) * cpx + blockIdx.x / N_XCD;
    int t = chunk * 256 + threadIdx.x;
    int total = n_rois * CH * OUT_H * OUT_W;
    if (t >= total) return;

    int per_c = n_rois * (OUT_H * OUT_W);
    int c = t / per_c;
    int rem = t - c * per_c;
    int n = rem / (OUT_H * OUT_W);
    int pq = rem - n * (OUT_H * OUT_W);
    int q = pq % OUT_W;
    int p = pq / OUT_W;

    const float* r = rois + n * 5;
    int b = (int)r[0];
    float x1 = r[1] * SPATIAL_SCALE;
    float y1 = r[2] * SPATIAL_SCALE;
    float x2 = r[3] * SPATIAL_SCALE;
    float y2 = r[4] * SPATIAL_SCALE;
    float bw = fmaxf(x2 - x1, 0.0f) * (1.0f / OUT_W);
    float bh = fmaxf(y2 - y1, 0.0f) * (1.0f / OUT_H);

    float u0x = x1 + (float)q * bw, u1x = u0x + bw;
    float u0y = y1 + (float)p * bh, u1y = u0y + bh;

    // 8-px support window; x start rounded down to even (4B f16 alignment),
    // widened to 10 px so coverage is preserved; clamped in-image.
    int ws8 = min(max((int)ceilf(u0x - 1.0f), 0), FW - 8);
    int ws = min(ws8 & ~1, FW - SUPX);
    int hs = min(max((int)ceilf(u0y - 1.0f), 0), FH - SUP);

    float wxf[SUPX], wy[SUP];
    float dx0 = u0x - (float)ws, dx1 = u1x - (float)ws;
    float dy0 = u0y - (float)hs, dy1 = u1y - (float)hs;
#pragma unroll
    for (int j = 0; j < SUPX; ++j) {
        wxf[j] = hat_cdf_c(dx1) - hat_cdf_c(dx0);
        dx0 -= 1.0f; dx1 -= 1.0f;
    }
#pragma unroll
    for (int i = 0; i < SUP; ++i) {
        wy[i] = hat_cdf_c(dy1) - hat_cdf_c(dy0);
        dy0 -= 1.0f; dy1 -= 1.0f;
    }
    h2 wxh[5];
#pragma unroll
    for (int k = 0; k < 5; ++k)
        wxh[k] = h2{(_Float16)wxf[2 * k], (_Float16)wxf[2 * k + 1]};

    const _Float16* fb = feat + (((size_t)b * CH + c) * FH + hs) * FW + ws;
    float acc0 = 0.0f, acc1 = 0.0f;
#pragma unroll
    for (int i = 0; i < SUP; ++i) {
        const _Float16* row = fb + i * FW;
        h8 v = *reinterpret_cast<const h8*>(row);
        h2 v4 = *reinterpret_cast<const h2*>(row + 8);
        float rsA = dot2f(__builtin_shufflevector(v, v, 0, 1), wxh[0], 0.0f);
        rsA = dot2f(__builtin_shufflevector(v, v, 2, 3), wxh[1], rsA);
        float rsB = dot2f(__builtin_shufflevector(v, v, 4, 5), wxh[2], 0.0f);
        rsB = dot2f(__builtin_shufflevector(v, v, 6, 7), wxh[3], rsB);
        rsB = dot2f(v4, wxh[4], rsB);
        acc0 = fmaf(wy[i], rsA, acc0);
        acc1 = fmaf(wy[i], rsB, acc1);
    }
    float acc = acc0 + acc1;

    float area = bw * bh;
    float res = (area > 0.0f) ? acc / fmaxf(area, 1e-12f) : 0.0f;
    out[((size_t)n * CH + c) * (OUT_H * OUT_W) + pq] = res;
}

extern "C" void kernel_launch(void* const* d_in, const int* in_sizes, int n_in,
                              void* d_out, int out_size, void* d_ws, size_t ws_size,
                              hipStream_t stream) {
    const float* feat = (const float*)d_in[0];
    const float* rois = (const float*)d_in[1];
    float* out = (float*)d_out;
    _Float16* feat16 = (_Float16*)d_ws;

    int n_feat = in_sizes[0];           // 1,280,000
    int n8 = n_feat / 8;                // 160,000 (divisible)
    int cvt_blocks = (n8 + 255) / 256;  // 625
    hipLaunchKernelGGL(cvt_f32_f16_kernel, dim3(cvt_blocks), dim3(256), 0,
                       stream, feat, feat16, n8);

    int n_rois = in_sizes[1] / 5;
    int total = n_rois * CH * OUT_H * OUT_W;
    int blocks = (total + 255) / 256;   // 3136 = 8 * 392
    hipLaunchKernelGGL(prroi_pool_kernel, dim3(blocks), dim3(256), 0, stream,
                       feat16, rois, out, n_rois);
}

// Round 6
// 13.615 us; speedup vs baseline: 1.4751x; 1.4751x over previous
//
#include <hip/hip_runtime.h>

// PrRoIPool forward. features [2,64,100,100] f32, rois [256,5], out [256,64,7,7].
//
// Separable analytic integral of bilinear interp over each bin. x-window:
// fixed 8 px, start clamped to [0, FW-8] (out-of-support weights exactly 0).
// y-window: DYNAMIC row count (round-6 change) — only rows with nonzero hat
// support, hcount = floor(u1y+1) - ceil(u0y-1) + 1 in [1,8], mean ~5.6.
//
// Evidence through r5: time is invariant to VMEM/VALU instr count and L2
// locality; +1 trivial dispatch costs +5us. Surviving model: L1 data-return
// BW (256B/thread @ 64B/cyc/CU = 5.2us) + ~5us dispatch + ~5us ramp/latency.
// This round cuts returned bytes 30% by skipping zero-weight rows, with a
// 1-deep software pipeline (prefetch row i+1 during row i, last iter peeled)
// so the rolled loop doesn't expose load latency. wy computed on the fly
// (no runtime-indexed register arrays -> no scratch).

constexpr int OUT_H = 7, OUT_W = 7;
constexpr float SPATIAL_SCALE = 0.25f;
constexpr int CH = 64, FH = 100, FW = 100;
constexpr int SUPX = 8;
constexpr int N_XCD = 8;

typedef float f4u __attribute__((ext_vector_type(4), aligned(4)));

__device__ __forceinline__ float hat_cdf_c(float t) {
    // cdf(t) - 0.5 (constant cancels in differences): s=clamp(t,-1,1),
    // s*(1-|s|/2).  min(max()) -> v_med3_f32; |s| is a free input modifier.
    float s = fminf(fmaxf(t, -1.0f), 1.0f);
    return s * fmaf(-0.5f, fabsf(s), 1.0f);
}

__global__ __launch_bounds__(256) void prroi_pool_kernel(
    const float* __restrict__ feat, const float* __restrict__ rois,
    float* __restrict__ out, int n_rois) {
    // Bijective XCD swizzle (nwg = 3136 = 8*392) + c-major decode: XCD k
    // touches only channels [8k, 8k+8) -> per-XCD working set L2-resident.
    int nwg = gridDim.x;
    int cpx = nwg / N_XCD;
    int chunk = (blockIdx.x % N_XCD) * cpx + blockIdx.x / N_XCD;
    int t = chunk * 256 + threadIdx.x;
    int total = n_rois * CH * OUT_H * OUT_W;
    if (t >= total) return;

    int per_c = n_rois * (OUT_H * OUT_W);
    int c = t / per_c;
    int rem = t - c * per_c;
    int n = rem / (OUT_H * OUT_W);
    int pq = rem - n * (OUT_H * OUT_W);
    int q = pq % OUT_W;
    int p = pq / OUT_W;

    const float* r = rois + n * 5;
    int b = (int)r[0];
    float x1 = r[1] * SPATIAL_SCALE;
    float y1 = r[2] * SPATIAL_SCALE;
    float x2 = r[3] * SPATIAL_SCALE;
    float y2 = r[4] * SPATIAL_SCALE;
    float bw = fmaxf(x2 - x1, 0.0f) * (1.0f / OUT_W);
    float bh = fmaxf(y2 - y1, 0.0f) * (1.0f / OUT_H);

    float u0x = x1 + (float)q * bw, u1x = u0x + bw;
    float u0y = y1 + (float)p * bh, u1y = u0y + bh;

    // x: fixed 8-px window, clamped in-image.
    int ws = min(max((int)ceilf(u0x - 1.0f), 0), FW - SUPX);
    // y: exact support rows [hs, he], 1..8 rows, each individually in-image.
    int hs = max((int)ceilf(u0y - 1.0f), 0);
    int he = min((int)floorf(u1y + 1.0f), FH - 1);
    int hcount = he - hs + 1;
    if (hcount < 1) hcount = 1;

    float wx[SUPX];
    float dx0 = u0x - (float)ws, dx1 = u1x - (float)ws;
#pragma unroll
    for (int j = 0; j < SUPX; ++j) {
        wx[j] = hat_cdf_c(dx1) - hat_cdf_c(dx0);
        dx0 -= 1.0f; dx1 -= 1.0f;
    }

    const float* base = feat + (((size_t)b * CH + c) * FH) * FW + ws;

    // 1-deep pipelined y loop: va/vb hold row i; prefetch row i+1.
    const float* row0 = base + hs * FW;
    f4u va = *reinterpret_cast<const f4u*>(row0);
    f4u vb = *reinterpret_cast<const f4u*>(row0 + 4);
    float d0 = u0y - (float)hs, d1 = u1y - (float)hs;
    float acc0 = 0.0f, acc1 = 0.0f;

    for (int i = 0; i < hcount - 1; ++i) {
        const float* rn = base + (hs + i + 1) * FW;
        f4u na = *reinterpret_cast<const f4u*>(rn);
        f4u nb = *reinterpret_cast<const f4u*>(rn + 4);
        float wyi = hat_cdf_c(d1) - hat_cdf_c(d0);
        d0 -= 1.0f; d1 -= 1.0f;
        float rsA = fmaf(wx[0], va.x,
                    fmaf(wx[1], va.y,
                    fmaf(wx[2], va.z, wx[3] * va.w)));
        float rsB = fmaf(wx[4], vb.x,
                    fmaf(wx[5], vb.y,
                    fmaf(wx[6], vb.z, wx[7] * vb.w)));
        acc0 = fmaf(wyi, rsA, acc0);
        acc1 = fmaf(wyi, rsB, acc1);
        va = na; vb = nb;
    }
    // last row (no prefetch)
    {
        float wyi = hat_cdf_c(d1) - hat_cdf_c(d0);
        float rsA = fmaf(wx[0], va.x,
                    fmaf(wx[1], va.y,
                    fmaf(wx[2], va.z, wx[3] * va.w)));
        float rsB = fmaf(wx[4], vb.x,
                    fmaf(wx[5], vb.y,
                    fmaf(wx[6], vb.z, wx[7] * vb.w)));
        acc0 = fmaf(wyi, rsA, acc0);
        acc1 = fmaf(wyi, rsB, acc1);
    }
    float acc = acc0 + acc1;

    float area = bw * bh;
    float res = (area > 0.0f) ? acc / fmaxf(area, 1e-12f) : 0.0f;
    out[((size_t)n * CH + c) * (OUT_H * OUT_W) + pq] = res;
}

extern "C" void kernel_launch(void* const* d_in, const int* in_sizes, int n_in,
                              void* d_out, int out_size, void* d_ws, size_t ws_size,
                              hipStream_t stream) {
    const float* feat = (const float*)d_in[0];
    const float* rois = (const float*)d_in[1];
    float* out = (float*)d_out;
    int n_rois = in_sizes[1] / 5;
    int total = n_rois * CH * OUT_H * OUT_W;
    int blocks = (total + 255) / 256;  // 3136 = 8 * 392
    hipLaunchKernelGGL(prroi_pool_kernel, dim3(blocks), dim3(256), 0, stream,
                       feat, rois, out, n_rois);
}

// Round 7
// 13.473 us; speedup vs baseline: 1.4907x; 1.0106x over previous
//
#include <hip/hip_runtime.h>

// PrRoIPool forward. features [2,64,100,100] f32, rois [256,5], out [256,64,7,7].
//
// Separable analytic integral of bilinear interp over each bin. x: fixed 8-px
// window (2x float4, unaligned ok), start clamped in-image; out-of-support
// weights are exactly zero. y: dynamic row range covering the UNION of two
// vertically-adjacent bins' supports (round-7 change).
//
// Confirmed model (r1-r6): time = ~5us dispatch overhead + data-return bytes
// (L1/L2, ~64B/cyc/CU) + latency/tail. r6 cut bytes 30% -> -1.5us, matching.
// r7: one thread computes bins (p0=2k, p1=2k+1): union support = 2bh+2 rows
// (mean 8.7) vs 2*(bh+2) separate (11.2) -> bytes/output -22%; each loaded
// row feeds both bins' accumulators with independent on-the-fly wy weights.
// Thread count 802816 -> 458752 (7168 waves): single occupancy round, no
// second-round tail. k=3 handles p=6 alone (dp=0, second store skipped).

constexpr int OUT_H = 7, OUT_W = 7;
constexpr float SPATIAL_SCALE = 0.25f;
constexpr int CH = 64, FH = 100, FW = 100;
constexpr int SUPX = 8;
constexpr int N_XCD = 8;

typedef float f4u __attribute__((ext_vector_type(4), aligned(4)));

__device__ __forceinline__ float hat_cdf_c(float t) {
    // cdf(t) - 0.5 (constant cancels in differences): s=clamp(t,-1,1),
    // s*(1-|s|/2).  min(max()) -> v_med3_f32; |s| is a free input modifier.
    float s = fminf(fmaxf(t, -1.0f), 1.0f);
    return s * fmaf(-0.5f, fabsf(s), 1.0f);
}

__global__ __launch_bounds__(256) void prroi_pool_kernel(
    const float* __restrict__ feat, const float* __restrict__ rois,
    float* __restrict__ out, int n_rois) {
    // Bijective XCD swizzle (nwg = 1792 = 8*224) + c-major decode: XCD k
    // touches only channels [8k, 8k+8) -> per-XCD working set L2-resident.
    int nwg = gridDim.x;
    int cpx = nwg / N_XCD;
    int chunk = (blockIdx.x % N_XCD) * cpx + blockIdx.x / N_XCD;
    int t = chunk * 256 + threadIdx.x;
    int total = n_rois * CH * 4 * OUT_W;
    if (t >= total) return;

    // item = ((c*n_rois + n)*4 + k)*7 + q ; thread covers p0=2k (and p1=2k+1)
    int q = t % OUT_W;
    int rest = t / OUT_W;
    int k = rest & 3;
    rest >>= 2;
    int n = rest % n_rois;
    int c = rest / n_rois;
    int p0 = 2 * k;
    int dp = (k < 3) ? 1 : 0;  // k=3 -> single bin p=6

    const float* r = rois + n * 5;
    int b = (int)r[0];
    float x1 = r[1] * SPATIAL_SCALE;
    float y1 = r[2] * SPATIAL_SCALE;
    float x2 = r[3] * SPATIAL_SCALE;
    float y2 = r[4] * SPATIAL_SCALE;
    float bw = fmaxf(x2 - x1, 0.0f) * (1.0f / OUT_W);
    float bh = fmaxf(y2 - y1, 0.0f) * (1.0f / OUT_H);

    float u0x = x1 + (float)q * bw, u1x = u0x + bw;
    float u0yA = y1 + (float)p0 * bh;          // bin A = [u0yA, u0yA+bh]
    float u1yB = y1 + (float)(p0 + dp + 1) * bh;  // bottom of bin B

    // x: fixed 8-px window, clamped in-image.
    int ws = min(max((int)ceilf(u0x - 1.0f), 0), FW - SUPX);
    // y: union support rows [hs, he] of bins A and B (contiguous: adjacent
    // bins' hat supports overlap by 2 rows).
    int hs = max((int)ceilf(u0yA - 1.0f), 0);
    int he = min((int)floorf(u1yB + 1.0f), FH - 1);
    int hcount = he - hs + 1;
    if (hcount < 1) hcount = 1;

    float wx[SUPX];
    float dx0 = u0x - (float)ws, dx1 = u1x - (float)ws;
#pragma unroll
    for (int j = 0; j < SUPX; ++j) {
        wx[j] = hat_cdf_c(dx1) - hat_cdf_c(dx0);
        dx0 -= 1.0f; dx1 -= 1.0f;
    }

    const float* base = feat + (((size_t)b * CH + c) * FH) * FW + ws;

    // Incremental wy arguments for both bins.
    float dA0 = u0yA - (float)hs, dA1 = dA0 + bh;
    float dB0 = dA0 + (float)dp * bh, dB1 = dB0 + bh;

    // 1-deep pipelined y loop: va/vb hold row i; prefetch row i+1.
    const float* row0 = base + hs * FW;
    f4u va = *reinterpret_cast<const f4u*>(row0);
    f4u vb = *reinterpret_cast<const f4u*>(row0 + 4);
    float accA = 0.0f, accB = 0.0f;

    for (int i = 0; i < hcount - 1; ++i) {
        const float* rn = base + (hs + i + 1) * FW;
        f4u na = *reinterpret_cast<const f4u*>(rn);
        f4u nb = *reinterpret_cast<const f4u*>(rn + 4);
        float wyA = hat_cdf_c(dA1) - hat_cdf_c(dA0);
        float wyB = hat_cdf_c(dB1) - hat_cdf_c(dB0);
        dA0 -= 1.0f; dA1 -= 1.0f; dB0 -= 1.0f; dB1 -= 1.0f;
        float rsA = fmaf(wx[0], va.x,
                    fmaf(wx[1], va.y,
                    fmaf(wx[2], va.z, wx[3] * va.w)));
        float rsB = fmaf(wx[4], vb.x,
                    fmaf(wx[5], vb.y,
                    fmaf(wx[6], vb.z, wx[7] * vb.w)));
        float rs = rsA + rsB;
        accA = fmaf(wyA, rs, accA);
        accB = fmaf(wyB, rs, accB);
        va = na; vb = nb;
    }
    // last row (no prefetch)
    {
        float wyA = hat_cdf_c(dA1) - hat_cdf_c(dA0);
        float wyB = hat_cdf_c(dB1) - hat_cdf_c(dB0);
        float rsA = fmaf(wx[0], va.x,
                    fmaf(wx[1], va.y,
                    fmaf(wx[2], va.z, wx[3] * va.w)));
        float rsB = fmaf(wx[4], vb.x,
                    fmaf(wx[5], vb.y,
                    fmaf(wx[6], vb.z, wx[7] * vb.w)));
        float rs = rsA + rsB;
        accA = fmaf(wyA, rs, accA);
        accB = fmaf(wyB, rs, accB);
    }

    float area = bw * bh;
    float inv = 1.0f / fmaxf(area, 1e-12f);
    bool ok = area > 0.0f;
    size_t obase = ((size_t)n * CH + c) * (OUT_H * OUT_W) + q;
    out[obase + (size_t)p0 * OUT_W] = ok ? accA * inv : 0.0f;
    if (dp) out[obase + (size_t)(p0 + 1) * OUT_W] = ok ? accB * inv : 0.0f;
}

extern "C" void kernel_launch(void* const* d_in, const int* in_sizes, int n_in,
                              void* d_out, int out_size, void* d_ws, size_t ws_size,
                              hipStream_t stream) {
    const float* feat = (const float*)d_in[0];
    const float* rois = (const float*)d_in[1];
    float* out = (float*)d_out;
    int n_rois = in_sizes[1] / 5;
    int total = n_rois * CH * 4 * OUT_W;      // 458752
    int blocks = (total + 255) / 256;         // 1792 = 8 * 224
    hipLaunchKernelGGL(prroi_pool_kernel, dim3(blocks), dim3(256), 0, stream,
                       feat, rois, out, n_rois);
}